// Round 1
// baseline (899.899 us; speedup 1.0000x reference)
//
#include <hip/hip_runtime.h>
#include <hip/hip_bf16.h>
#include <cstdint>

#define NTOK 4096
#define NEXP 16
#define HID 2048
#define INTER 1408
#define BK 32
#define LDA 40          // 32 + 8 pad (bf16 elems), rows are 80 B (16B-aligned)
#define MAXTILES 80     // sum ceil(c_e/128) <= 8192/128 + 16 = 80
#define GU_NB 22        // INTER/64 n-blocks for gateup
#define DN_NB 32        // HID/64 n-blocks for down
#define GU_GRID (GU_NB * MAXTILES)   // 1760, %8==0
#define DN_GRID (DN_NB * MAXTILES)   // 2560, %8==0

typedef __attribute__((ext_vector_type(8))) short bf16x8;
typedef __attribute__((ext_vector_type(4))) float f32x4;

// ws int layout:
//   [0..15]=counts [16..31]=cursors [32..47]=offsets [48]=tile_count
//   [64..143]=tile_e [144..223]=tile_mt
//   [256..]=topk_id(8192) [8448..]=topk_w(8192)
//   [16640..]=list_tok(8192) [24832..]=list_w(8192) [33024..]=slot_of(8192)
// byte 262144: act bf16[8192][1408] (23,068,672 B)
// byte 23330816: AbY bf16[8192][2048] (33,554,432 B)  -- gathered A, later reused as y
// total ~56.9 MB

__device__ inline unsigned pack_bf16(float lo, float hi) {
  unsigned a = __builtin_bit_cast(unsigned, lo) + 0x8000u;
  unsigned b = __builtin_bit_cast(unsigned, hi) + 0x8000u;
  return __builtin_amdgcn_perm(b, a, 0x07060302u); // {b[31:16], a[31:16]}
}

__global__ void k_router(const float* __restrict__ logits, int* __restrict__ topk_id,
                         float* __restrict__ topk_w, int* __restrict__ counts) {
  int t = blockIdx.x * blockDim.x + threadIdx.x;
  if (t >= NTOK) return;
  const float* l = logits + (size_t)t * NEXP;
  float b0 = -1e30f, b1 = -1e30f; int i0 = 0, i1 = 0;
#pragma unroll
  for (int i = 0; i < NEXP; i++) {
    float v = l[i];
    if (v > b0) { b1 = b0; i1 = i0; b0 = v; i0 = i; }
    else if (v > b1) { b1 = v; i1 = i; }
  }
  float e = __expf(b1 - b0);
  float inv = 1.f / (1.f + e);
  topk_id[t * 2] = i0; topk_id[t * 2 + 1] = i1;
  topk_w[t * 2] = inv; topk_w[t * 2 + 1] = e * inv;
  atomicAdd(&counts[i0], 1);
  atomicAdd(&counts[i1], 1);
}

__global__ void k_build(int* __restrict__ ws_i) {
  if (threadIdx.x == 0) {
    int off = 0, nt = 0;
    for (int e = 0; e < NEXP; e++) {
      int c = ws_i[e];
      ws_i[32 + e] = off;
      int tiles = (c + 127) >> 7;
      for (int mt = 0; mt < tiles; mt++) { ws_i[64 + nt] = e; ws_i[144 + nt] = mt; nt++; }
      off += c;
    }
    ws_i[48] = nt;
  }
}

__global__ void k_scatter(const int* __restrict__ topk_id, const float* __restrict__ topk_w,
                          int* __restrict__ ws_i, int* __restrict__ list_tok,
                          float* __restrict__ list_w, int* __restrict__ slot_of) {
  int t = blockIdx.x * blockDim.x + threadIdx.x;
  if (t >= NTOK) return;
#pragma unroll
  for (int k = 0; k < 2; k++) {
    int e = topk_id[t * 2 + k];
    int slot = ws_i[32 + e] + atomicAdd(&ws_i[16 + e], 1);
    list_tok[slot] = t;
    list_w[slot] = topk_w[t * 2 + k];
    slot_of[t * 2 + k] = slot;
  }
}

// gather hidden rows per slot, convert fp32->bf16. One block per slot row.
__global__ __launch_bounds__(256) void k_gather(const float* __restrict__ hidden,
                                                const int* __restrict__ list_tok,
                                                unsigned short* __restrict__ Ab) {
  int s = blockIdx.x, tx = threadIdx.x;
  int t = list_tok[s];
  const float4* src = (const float4*)(hidden + (size_t)t * HID) + tx * 2;
  float4 a = src[0], b = src[1];
  uint4 w = make_uint4(pack_bf16(a.x, a.y), pack_bf16(a.z, a.w),
                       pack_bf16(b.x, b.y), pack_bf16(b.z, b.w));
  ((uint4*)(Ab + (size_t)s * HID))[tx] = w;
}

// gate+up fused GEMM + SwiGLU. Block tile: 128m x 64n (x2 for g,u), 4 waves (2m x 2n).
// 1D grid, expert-major work order w = tileId*22 + n, XCD-chunked so that one
// XCD's in-flight blocks cover ~one expert: A tiles (2 MB) + same-n B-panel
// re-reads (distance 22 work items) stay resident in that XCD's 4 MB L2.
__global__ __launch_bounds__(256, 4) void k_gateup(
    const unsigned short* __restrict__ Ab, const float* __restrict__ w_gate,
    const float* __restrict__ w_up, const int* __restrict__ ws_i,
    __hip_bfloat16* __restrict__ act) {
  __shared__ unsigned short sA[128 * LDA];
  __shared__ unsigned short sBg[64 * LDA];
  __shared__ unsigned short sBu[64 * LDA];

  int bid = blockIdx.x;
  int w = (bid & 7) * (GU_GRID / 8) + (bid >> 3);  // XCD-chunked bijection
  int tileId = w / GU_NB;
  int n0 = (w - tileId * GU_NB) * 64;
  if (tileId >= ws_i[48]) return;
  int e = ws_i[64 + tileId];
  int mt = ws_i[144 + tileId];
  int c = ws_i[e];
  int offE = ws_i[32 + e];
  int m0 = mt * 128;
  int tid = threadIdx.x;

  int lane = tid & 63;
  int wave = tid >> 6;
  int wm = wave & 1, wn = wave >> 1;

  // A staging: 2 threads per row, 32 B (16 bf16) each
  int ar = tid >> 1;
  int ah = (tid & 1) * 16;
  int rA = m0 + ar; int rrA = rA < c ? rA : c - 1;
  const unsigned short* aSrc = Ab + (size_t)(offE + rrA) * HID + ah;

  // B staging: 64 cols x 32 k per iter; thread -> (col bn, k-group bkg of 8)
  int bn = tid & 63;
  int bkg = tid >> 6;
  const float* bgSrc = w_gate + (size_t)e * HID * INTER + n0 + bn + (size_t)(bkg * 8) * INTER;
  const float* buSrc = w_up   + (size_t)e * HID * INTER + n0 + bn + (size_t)(bkg * 8) * INTER;

  f32x4 accG[4][2], accU[4][2];
#pragma unroll
  for (int i = 0; i < 4; i++)
#pragma unroll
    for (int j = 0; j < 2; j++) { accG[i][j] = (f32x4)(0.f); accU[i][j] = (f32x4)(0.f); }

  int kq = (lane >> 4) * 8;
  int ml = lane & 15;

  // prologue: prefetch k0 = 0
  uint4 a0r, a1r; float g[8], u[8];
  {
    const uint4* ap = (const uint4*)aSrc;
    a0r = ap[0]; a1r = ap[1];
#pragma unroll
    for (int j = 0; j < 8; j++) { g[j] = bgSrc[(size_t)j * INTER]; u[j] = buSrc[(size_t)j * INTER]; }
  }

  for (int k0 = 0; k0 < HID; k0 += BK) {
    __syncthreads();
    *(uint4*)&sA[ar * LDA + ah] = a0r;
    *(uint4*)&sA[ar * LDA + ah + 8] = a1r;
    *(uint4*)&sBg[bn * LDA + bkg * 8] = make_uint4(
        pack_bf16(g[0], g[1]), pack_bf16(g[2], g[3]),
        pack_bf16(g[4], g[5]), pack_bf16(g[6], g[7]));
    *(uint4*)&sBu[bn * LDA + bkg * 8] = make_uint4(
        pack_bf16(u[0], u[1]), pack_bf16(u[2], u[3]),
        pack_bf16(u[4], u[5]), pack_bf16(u[6], u[7]));
    __syncthreads();

    if (k0 + BK < HID) {
      const uint4* ap = (const uint4*)(aSrc + k0 + BK);
      a0r = ap[0]; a1r = ap[1];
      const float* bg = bgSrc + (size_t)(k0 + BK) * INTER;
      const float* bu = buSrc + (size_t)(k0 + BK) * INTER;
#pragma unroll
      for (int j = 0; j < 8; j++) { g[j] = bg[(size_t)j * INTER]; u[j] = bu[(size_t)j * INTER]; }
    }

    bf16x8 af[4], bgf[2], buf2[2];
#pragma unroll
    for (int ni = 0; ni < 2; ni++) {
      bgf[ni] = *(const bf16x8*)&sBg[(wn * 32 + ni * 16 + ml) * LDA + kq];
      buf2[ni] = *(const bf16x8*)&sBu[(wn * 32 + ni * 16 + ml) * LDA + kq];
    }
#pragma unroll
    for (int mi = 0; mi < 4; mi++)
      af[mi] = *(const bf16x8*)&sA[(wm * 64 + mi * 16 + ml) * LDA + kq];
#pragma unroll
    for (int mi = 0; mi < 4; mi++)
#pragma unroll
      for (int ni = 0; ni < 2; ni++) {
        accG[mi][ni] = __builtin_amdgcn_mfma_f32_16x16x32_bf16(af[mi], bgf[ni], accG[mi][ni], 0, 0, 0);
        accU[mi][ni] = __builtin_amdgcn_mfma_f32_16x16x32_bf16(af[mi], buf2[ni], accU[mi][ni], 0, 0, 0);
      }
  }

  // epilogue: act = silu(g)*u. C/D: col=lane&15, row=(lane>>4)*4+reg
  int rq = (lane >> 4) * 4;
#pragma unroll
  for (int mi = 0; mi < 4; mi++)
#pragma unroll
    for (int r = 0; r < 4; r++) {
      int mrow = wm * 64 + mi * 16 + rq + r;
      int mglob = m0 + mrow;
      if (mglob < c) {
        size_t arow = (size_t)(offE + mglob);
#pragma unroll
        for (int ni = 0; ni < 2; ni++) {
          float gv = accG[mi][ni][r], uv = accU[mi][ni][r];
          float av = gv / (1.f + __expf(-gv)) * uv;
          int ncol = n0 + wn * 32 + ni * 16 + ml;
          act[arow * INTER + ncol] = __float2bfloat16(av);
        }
      }
    }
}

// down GEMM, weighted, atomic-free: writes y[slot][HID] bf16. Block tile 128m x 64n.
// Same XCD-chunked expert-major work order (chunk 320, 32 n-blocks).
__global__ __launch_bounds__(256, 4) void k_down(
    const __hip_bfloat16* __restrict__ act, const float* __restrict__ w_down,
    const int* __restrict__ ws_i, const float* __restrict__ list_w,
    unsigned short* __restrict__ y) {
  __shared__ unsigned short sA[128 * LDA];
  __shared__ unsigned short sB[64 * LDA];
  __shared__ float sW[128];

  int bid = blockIdx.x;
  int w = (bid & 7) * (DN_GRID / 8) + (bid >> 3);  // XCD-chunked bijection
  int tileId = w >> 5;
  int n0 = (w & 31) * 64;
  if (tileId >= ws_i[48]) return;
  int e = ws_i[64 + tileId];
  int mt = ws_i[144 + tileId];
  int c = ws_i[e];
  int offE = ws_i[32 + e];
  int m0 = mt * 128;
  int tid = threadIdx.x;

  if (tid < 128) {
    int r = m0 + tid;
    int rr = r < c ? r : c - 1;
    sW[tid] = list_w[offE + rr];
  }

  int lane = tid & 63;
  int wave = tid >> 6;
  int wm = wave & 1, wn = wave >> 1;
  f32x4 acc[4][2];
#pragma unroll
  for (int i = 0; i < 4; i++)
#pragma unroll
    for (int j = 0; j < 2; j++) acc[i][j] = (f32x4)(0.f);

  int ar = tid >> 1;
  int ah = (tid & 1) * 16;
  int rA = m0 + ar; int rrA = rA < c ? rA : c - 1;
  const unsigned short* aSrc = (const unsigned short*)act + (size_t)(offE + rrA) * INTER + ah;

  int bn = tid & 63;
  int bkg = tid >> 6;
  const float* bSrc = w_down + (size_t)e * INTER * HID + (size_t)(bkg * 8) * HID + n0 + bn;

  int kq = (lane >> 4) * 8;
  int ml = lane & 15;

  uint4 a0r, a1r; float b[8];
  {
    const uint4* ap = (const uint4*)aSrc;
    a0r = ap[0]; a1r = ap[1];
#pragma unroll
    for (int j = 0; j < 8; j++) b[j] = bSrc[(size_t)j * HID];
  }

  for (int k0 = 0; k0 < INTER; k0 += BK) {
    __syncthreads();
    *(uint4*)&sA[ar * LDA + ah] = a0r;
    *(uint4*)&sA[ar * LDA + ah + 8] = a1r;
    *(uint4*)&sB[bn * LDA + bkg * 8] = make_uint4(
        pack_bf16(b[0], b[1]), pack_bf16(b[2], b[3]),
        pack_bf16(b[4], b[5]), pack_bf16(b[6], b[7]));
    __syncthreads();

    if (k0 + BK < INTER) {
      const uint4* ap = (const uint4*)(aSrc + k0 + BK);
      a0r = ap[0]; a1r = ap[1];
      const float* bp = bSrc + (size_t)(k0 + BK) * HID;
#pragma unroll
      for (int j = 0; j < 8; j++) b[j] = bp[(size_t)j * HID];
    }

    bf16x8 af[4], bf[2];
#pragma unroll
    for (int ni = 0; ni < 2; ni++)
      bf[ni] = *(const bf16x8*)&sB[(wn * 32 + ni * 16 + ml) * LDA + kq];
#pragma unroll
    for (int mi = 0; mi < 4; mi++)
      af[mi] = *(const bf16x8*)&sA[(wm * 64 + mi * 16 + ml) * LDA + kq];
#pragma unroll
    for (int mi = 0; mi < 4; mi++)
#pragma unroll
      for (int ni = 0; ni < 2; ni++)
        acc[mi][ni] = __builtin_amdgcn_mfma_f32_16x16x32_bf16(af[mi], bf[ni], acc[mi][ni], 0, 0, 0);
  }

  int rq = (lane >> 4) * 4;
#pragma unroll
  for (int mi = 0; mi < 4; mi++)
#pragma unroll
    for (int r = 0; r < 4; r++) {
      int mrow = wm * 64 + mi * 16 + rq + r;
      if (m0 + mrow < c) {
        float w2 = sW[mrow];
        size_t yrow = (size_t)(offE + m0 + mrow);
#pragma unroll
        for (int ni = 0; ni < 2; ni++) {
          int ncol = n0 + wn * 32 + ni * 16 + ml;
          float v = w2 * acc[mi][ni][r];
          y[yrow * HID + ncol] = (unsigned short)(pack_bf16(v, 0.f) & 0xffffu);
        }
      }
    }
}

// out[t] = y[slot0] + y[slot1], full coalesced row writes (covers every element).
__global__ __launch_bounds__(256) void k_combine(const unsigned short* __restrict__ y,
                                                 const int* __restrict__ slot_of,
                                                 float* __restrict__ out) {
  int t = blockIdx.x, tx = threadIdx.x;
  size_t s0 = (size_t)slot_of[t * 2], s1 = (size_t)slot_of[t * 2 + 1];
  uint4 v0 = ((const uint4*)(y + s0 * HID))[tx];
  uint4 v1 = ((const uint4*)(y + s1 * HID))[tx];
  float r[8];
  unsigned p0[4] = {v0.x, v0.y, v0.z, v0.w};
  unsigned p1[4] = {v1.x, v1.y, v1.z, v1.w};
#pragma unroll
  for (int i = 0; i < 4; i++) {
    float lo0 = __builtin_bit_cast(float, p0[i] << 16);
    float hi0 = __builtin_bit_cast(float, p0[i] & 0xffff0000u);
    float lo1 = __builtin_bit_cast(float, p1[i] << 16);
    float hi1 = __builtin_bit_cast(float, p1[i] & 0xffff0000u);
    r[i * 2] = lo0 + lo1; r[i * 2 + 1] = hi0 + hi1;
  }
  float4* op = (float4*)(out + (size_t)t * HID) + tx * 2;
  op[0] = make_float4(r[0], r[1], r[2], r[3]);
  op[1] = make_float4(r[4], r[5], r[6], r[7]);
}

extern "C" void kernel_launch(void* const* d_in, const int* in_sizes, int n_in,
                              void* d_out, int out_size, void* d_ws, size_t ws_size,
                              hipStream_t stream) {
  const float* hidden = (const float*)d_in[0];
  const float* logits = (const float*)d_in[1];
  const float* w_gate = (const float*)d_in[2];
  const float* w_up = (const float*)d_in[3];
  const float* w_down = (const float*)d_in[4];
  float* out = (float*)d_out;

  int* ws_i = (int*)d_ws;
  int* topk_id = ws_i + 256;
  float* topk_w = (float*)(ws_i + 8448);
  int* list_tok = ws_i + 16640;
  float* list_w = (float*)(ws_i + 24832);
  int* slot_of = ws_i + 33024;
  __hip_bfloat16* act = (__hip_bfloat16*)((char*)d_ws + 262144);
  unsigned short* AbY = (unsigned short*)((char*)d_ws + 23330816);  // gathered A, then y

  hipMemsetAsync(d_ws, 0, 256 * 4, stream);  // counts/cursors/tile_count

  k_router<<<NTOK / 256, 256, 0, stream>>>(logits, topk_id, topk_w, ws_i);
  k_build<<<1, 64, 0, stream>>>(ws_i);
  k_scatter<<<NTOK / 256, 256, 0, stream>>>(topk_id, topk_w, ws_i, list_tok, list_w, slot_of);
  k_gather<<<NTOK * 2, 256, 0, stream>>>(hidden, list_tok, AbY);
  k_gateup<<<GU_GRID, 256, 0, stream>>>(AbY, w_gate, w_up, ws_i, act);
  k_down<<<DN_GRID, 256, 0, stream>>>(act, w_down, ws_i, list_w, AbY);
  k_combine<<<NTOK, 256, 0, stream>>>(AbY, slot_of, out);
}

// Round 2
// 854.167 us; speedup vs baseline: 1.0535x; 1.0535x over previous
//
#include <hip/hip_runtime.h>
#include <hip/hip_bf16.h>
#include <cstdint>

#define NTOK 4096
#define NEXP 16
#define HID 2048
#define INTER 1408
#define BK 32
#define LDA 40          // old path: 32 + 8 pad
#define MAXTILES 80
#define GU_NB 22        // INTER/64 n-blocks (both paths)
#define DN_NB 32        // old path: HID/64
#define DN_NB2 16       // new path: HID/128
#define GU_GRID (GU_NB * MAXTILES)    // 1760, %8==0
#define DN_GRID (DN_NB * MAXTILES)    // 2560, %8==0
#define DN_GRID2 (DN_NB2 * MAXTILES)  // 1280, %8==0

// bf16 transposed weight buffers (new path only)
#define WGT_OFF 56885248ull
#define WUT_OFF (WGT_OFF + 92274688ull)
#define WDT_OFF (WUT_OFF + 92274688ull)
#define WS_NEED (WDT_OFF + 92274688ull)   // ~334 MB

typedef __attribute__((ext_vector_type(8))) short bf16x8;
typedef __attribute__((ext_vector_type(4))) float f32x4;

__device__ inline unsigned pack_bf16(float lo, float hi) {
  unsigned a = __builtin_bit_cast(unsigned, lo) + 0x8000u;
  unsigned b = __builtin_bit_cast(unsigned, hi) + 0x8000u;
  return __builtin_amdgcn_perm(b, a, 0x07060302u); // {b[31:16], a[31:16]}
}

// global -> LDS direct 16B staging. LDS dest is wave-uniform base + lane*16.
// Generic->AS3 via 32-bit truncation (generic LDS ptr = aperture_hi | offset_lo).
typedef __attribute__((address_space(3))) void lds_vt;
typedef __attribute__((address_space(1))) const void glob_vt;
__device__ __forceinline__ void gload16(const void* g, void* l) {
  __builtin_amdgcn_global_load_lds(
      (glob_vt*)(unsigned long long)g,
      (lds_vt*)(unsigned)(unsigned long long)l, 16, 0, 0);
}

__global__ void k_router(const float* __restrict__ logits, int* __restrict__ topk_id,
                         float* __restrict__ topk_w, int* __restrict__ counts) {
  int t = blockIdx.x * blockDim.x + threadIdx.x;
  if (t >= NTOK) return;
  const float* l = logits + (size_t)t * NEXP;
  float b0 = -1e30f, b1 = -1e30f; int i0 = 0, i1 = 0;
#pragma unroll
  for (int i = 0; i < NEXP; i++) {
    float v = l[i];
    if (v > b0) { b1 = b0; i1 = i0; b0 = v; i0 = i; }
    else if (v > b1) { b1 = v; i1 = i; }
  }
  float e = __expf(b1 - b0);
  float inv = 1.f / (1.f + e);
  topk_id[t * 2] = i0; topk_id[t * 2 + 1] = i1;
  topk_w[t * 2] = inv; topk_w[t * 2 + 1] = e * inv;
  atomicAdd(&counts[i0], 1);
  atomicAdd(&counts[i1], 1);
}

__global__ void k_build(int* __restrict__ ws_i) {
  if (threadIdx.x == 0) {
    int off = 0, nt = 0;
    for (int e = 0; e < NEXP; e++) {
      int c = ws_i[e];
      ws_i[32 + e] = off;
      int tiles = (c + 127) >> 7;
      for (int mt = 0; mt < tiles; mt++) { ws_i[64 + nt] = e; ws_i[144 + nt] = mt; nt++; }
      off += c;
    }
    ws_i[48] = nt;
  }
}

__global__ void k_scatter(const int* __restrict__ topk_id, const float* __restrict__ topk_w,
                          int* __restrict__ ws_i, int* __restrict__ list_tok,
                          float* __restrict__ list_w, int* __restrict__ slot_of) {
  int t = blockIdx.x * blockDim.x + threadIdx.x;
  if (t >= NTOK) return;
#pragma unroll
  for (int k = 0; k < 2; k++) {
    int e = topk_id[t * 2 + k];
    int slot = ws_i[32 + e] + atomicAdd(&ws_i[16 + e], 1);
    list_tok[slot] = t;
    list_w[slot] = topk_w[t * 2 + k];
    slot_of[t * 2 + k] = slot;
  }
}

__global__ __launch_bounds__(256) void k_gather(const float* __restrict__ hidden,
                                                const int* __restrict__ list_tok,
                                                unsigned short* __restrict__ Ab) {
  int s = blockIdx.x, tx = threadIdx.x;
  int t = list_tok[s];
  const float4* src = (const float4*)(hidden + (size_t)t * HID) + tx * 2;
  float4 a = src[0], b = src[1];
  uint4 w = make_uint4(pack_bf16(a.x, a.y), pack_bf16(a.z, a.w),
                       pack_bf16(b.x, b.y), pack_bf16(b.z, b.w));
  ((uint4*)(Ab + (size_t)s * HID))[tx] = w;
}

// transpose-convert: src fp32 [E][R][C] -> dst bf16 [E][C][R]. 64x64 tiles via LDS.
__global__ __launch_bounds__(256) void k_tconv(const float* __restrict__ src,
                                               unsigned short* __restrict__ dst,
                                               int R, int C) {
  __shared__ unsigned short t[64][68];   // pad 68: 4B-aligned rows, conflict-light col reads
  int e = blockIdx.z, rb = blockIdx.y << 6, cb = blockIdx.x << 6;
  int tid = threadIdx.x;
  int lr = tid >> 2, q = tid & 3;
  const float* sp = src + (size_t)e * R * C + (size_t)(rb + lr) * C + cb + q * 16;
  float4 v0 = ((const float4*)sp)[0];
  float4 v1 = ((const float4*)sp)[1];
  float4 v2 = ((const float4*)sp)[2];
  float4 v3 = ((const float4*)sp)[3];
  unsigned* tp = (unsigned*)&t[lr][q * 16];
  tp[0] = pack_bf16(v0.x, v0.y); tp[1] = pack_bf16(v0.z, v0.w);
  tp[2] = pack_bf16(v1.x, v1.y); tp[3] = pack_bf16(v1.z, v1.w);
  tp[4] = pack_bf16(v2.x, v2.y); tp[5] = pack_bf16(v2.z, v2.w);
  tp[6] = pack_bf16(v3.x, v3.y); tp[7] = pack_bf16(v3.z, v3.w);
  __syncthreads();
  int oc = tid >> 2, seg = tid & 3;
  unsigned o[8];
#pragma unroll
  for (int i = 0; i < 8; i++) {
    unsigned lo = t[seg * 16 + 2 * i][oc];
    unsigned hi = t[seg * 16 + 2 * i + 1][oc];
    o[i] = lo | (hi << 16);
  }
  unsigned short* dp = dst + (size_t)e * R * C + (size_t)(cb + oc) * R + rb + seg * 16;
  ((uint4*)dp)[0] = make_uint4(o[0], o[1], o[2], o[3]);
  ((uint4*)dp)[1] = make_uint4(o[4], o[5], o[6], o[7]);
}

// ---------------- NEW PATH: m97-style GEMMs, global_load_lds staging ----------------

// gate+up GEMM + SwiGLU. Tile 128m x (64g + 64u), BK=32, linear LDS, 4 waves 2m x 2n.
__global__ __launch_bounds__(256, 3) void k_gateup_gl(
    const unsigned short* __restrict__ Ab, const unsigned short* __restrict__ wgT,
    const unsigned short* __restrict__ wuT, const int* __restrict__ ws_i,
    __hip_bfloat16* __restrict__ act) {
  __shared__ unsigned short sA[128 * BK];   // 8 KB, row = 64 B
  __shared__ unsigned short sBg[64 * BK];   // 4 KB
  __shared__ unsigned short sBu[64 * BK];   // 4 KB

  int bid = blockIdx.x;
  int w = (bid & 7) * (GU_GRID / 8) + (bid >> 3);  // XCD-chunked bijection
  int tileId = w / GU_NB;
  int n0 = (w - tileId * GU_NB) * 64;
  if (tileId >= ws_i[48]) return;
  int e = ws_i[64 + tileId];
  int mt = ws_i[144 + tileId];
  int c = ws_i[e];
  int offE = ws_i[32 + e];
  int m0 = mt * 128;
  int tid = threadIdx.x;
  int lane = tid & 63;
  int wave = tid >> 6;
  int wm = wave & 1, wn = wave >> 1;

  // staging: flat LDS byte s*16 for lane slot s; row = slot/4 (64 B rows), h = (slot%4)*16
  int la = lane >> 2;            // row within 16-row region
  int h = (lane & 3) * 16;       // byte within row
  int rA0 = (wave * 2 + 0) * 16 + la;
  int rA1 = (wave * 2 + 1) * 16 + la;
  int gr0 = m0 + rA0; gr0 = gr0 < c ? gr0 : c - 1;
  int gr1 = m0 + rA1; gr1 = gr1 < c ? gr1 : c - 1;
  const char* aBase0 = (const char*)(Ab + (size_t)(offE + gr0) * HID) + h;
  const char* aBase1 = (const char*)(Ab + (size_t)(offE + gr1) * HID) + h;
  char* ldsA0 = (char*)sA + (wave * 2 + 0) * 1024;
  char* ldsA1 = (char*)sA + (wave * 2 + 1) * 1024;

  int nB = wave * 16 + la;
  const char* bgBase = (const char*)(wgT + ((size_t)e * INTER + n0 + nB) * HID) + h;
  const char* buBase = (const char*)(wuT + ((size_t)e * INTER + n0 + nB) * HID) + h;
  char* ldsBg = (char*)sBg + wave * 1024;
  char* ldsBu = (char*)sBu + wave * 1024;

  f32x4 accG[4][2], accU[4][2];
#pragma unroll
  for (int i = 0; i < 4; i++)
#pragma unroll
    for (int j = 0; j < 2; j++) { accG[i][j] = (f32x4)(0.f); accU[i][j] = (f32x4)(0.f); }

  int kq = (lane >> 4) * 8;
  int ml = lane & 15;

  for (int k0 = 0; k0 < HID; k0 += BK) {
    __syncthreads();                       // prev-iter LDS reads done
    size_t kb = (size_t)k0 * 2;
    gload16(aBase0 + kb, ldsA0);
    gload16(aBase1 + kb, ldsA1);
    gload16(bgBase + kb, ldsBg);
    gload16(buBase + kb, ldsBu);
    __syncthreads();                       // vmcnt drain -> LDS ready

    bf16x8 af[4], bgf[2], buf2[2];
#pragma unroll
    for (int ni = 0; ni < 2; ni++) {
      bgf[ni] = *(const bf16x8*)&sBg[(wn * 32 + ni * 16 + ml) * BK + kq];
      buf2[ni] = *(const bf16x8*)&sBu[(wn * 32 + ni * 16 + ml) * BK + kq];
    }
#pragma unroll
    for (int mi = 0; mi < 4; mi++)
      af[mi] = *(const bf16x8*)&sA[(wm * 64 + mi * 16 + ml) * BK + kq];
#pragma unroll
    for (int mi = 0; mi < 4; mi++)
#pragma unroll
      for (int ni = 0; ni < 2; ni++) {
        accG[mi][ni] = __builtin_amdgcn_mfma_f32_16x16x32_bf16(af[mi], bgf[ni], accG[mi][ni], 0, 0, 0);
        accU[mi][ni] = __builtin_amdgcn_mfma_f32_16x16x32_bf16(af[mi], buf2[ni], accU[mi][ni], 0, 0, 0);
      }
  }

  int rq = (lane >> 4) * 4;
#pragma unroll
  for (int mi = 0; mi < 4; mi++)
#pragma unroll
    for (int r = 0; r < 4; r++) {
      int mrow = wm * 64 + mi * 16 + rq + r;
      int mglob = m0 + mrow;
      if (mglob < c) {
        size_t arow = (size_t)(offE + mglob);
#pragma unroll
        for (int ni = 0; ni < 2; ni++) {
          float gv = accG[mi][ni][r], uv = accU[mi][ni][r];
          float av = gv / (1.f + __expf(-gv)) * uv;
          int ncol = n0 + wn * 32 + ni * 16 + ml;
          act[arow * INTER + ncol] = __float2bfloat16(av);
        }
      }
    }
}

// down GEMM, weighted. Tile 128m x 128n, BK=32, linear LDS, 4 waves 2m x 2n.
__global__ __launch_bounds__(256, 3) void k_down_gl(
    const unsigned short* __restrict__ act, const unsigned short* __restrict__ wdT,
    const int* __restrict__ ws_i, const float* __restrict__ list_w,
    unsigned short* __restrict__ y) {
  __shared__ unsigned short sA[128 * BK];   // 8 KB
  __shared__ unsigned short sB[128 * BK];   // 8 KB
  __shared__ float sW[128];

  int bid = blockIdx.x;
  int w = (bid & 7) * (DN_GRID2 / 8) + (bid >> 3);
  int tileId = w >> 4;
  int n0 = (w & 15) * 128;
  if (tileId >= ws_i[48]) return;
  int e = ws_i[64 + tileId];
  int mt = ws_i[144 + tileId];
  int c = ws_i[e];
  int offE = ws_i[32 + e];
  int m0 = mt * 128;
  int tid = threadIdx.x;

  if (tid < 128) {
    int r = m0 + tid;
    int rr = r < c ? r : c - 1;
    sW[tid] = list_w[offE + rr];
  }

  int lane = tid & 63;
  int wave = tid >> 6;
  int wm = wave & 1, wn = wave >> 1;

  int la = lane >> 2;
  int h = (lane & 3) * 16;
  int rA0 = (wave * 2 + 0) * 16 + la;
  int rA1 = (wave * 2 + 1) * 16 + la;
  int gr0 = m0 + rA0; gr0 = gr0 < c ? gr0 : c - 1;
  int gr1 = m0 + rA1; gr1 = gr1 < c ? gr1 : c - 1;
  const char* aBase0 = (const char*)(act + (size_t)(offE + gr0) * INTER) + h;
  const char* aBase1 = (const char*)(act + (size_t)(offE + gr1) * INTER) + h;
  char* ldsA0 = (char*)sA + (wave * 2 + 0) * 1024;
  char* ldsA1 = (char*)sA + (wave * 2 + 1) * 1024;

  int rB0 = (wave * 2 + 0) * 16 + la;
  int rB1 = (wave * 2 + 1) * 16 + la;
  const char* bBase0 = (const char*)(wdT + ((size_t)e * HID + n0 + rB0) * INTER) + h;
  const char* bBase1 = (const char*)(wdT + ((size_t)e * HID + n0 + rB1) * INTER) + h;
  char* ldsB0 = (char*)sB + (wave * 2 + 0) * 1024;
  char* ldsB1 = (char*)sB + (wave * 2 + 1) * 1024;

  f32x4 acc[4][4];
#pragma unroll
  for (int i = 0; i < 4; i++)
#pragma unroll
    for (int j = 0; j < 4; j++) acc[i][j] = (f32x4)(0.f);

  int kq = (lane >> 4) * 8;
  int ml = lane & 15;

  for (int k0 = 0; k0 < INTER; k0 += BK) {
    __syncthreads();
    size_t kb = (size_t)k0 * 2;
    gload16(aBase0 + kb, ldsA0);
    gload16(aBase1 + kb, ldsA1);
    gload16(bBase0 + kb, ldsB0);
    gload16(bBase1 + kb, ldsB1);
    __syncthreads();

    bf16x8 af[4], bf[4];
#pragma unroll
    for (int ni = 0; ni < 4; ni++)
      bf[ni] = *(const bf16x8*)&sB[(wn * 64 + ni * 16 + ml) * BK + kq];
#pragma unroll
    for (int mi = 0; mi < 4; mi++)
      af[mi] = *(const bf16x8*)&sA[(wm * 64 + mi * 16 + ml) * BK + kq];
#pragma unroll
    for (int mi = 0; mi < 4; mi++)
#pragma unroll
      for (int ni = 0; ni < 4; ni++)
        acc[mi][ni] = __builtin_amdgcn_mfma_f32_16x16x32_bf16(af[mi], bf[ni], acc[mi][ni], 0, 0, 0);
  }

  int rq = (lane >> 4) * 4;
#pragma unroll
  for (int mi = 0; mi < 4; mi++)
#pragma unroll
    for (int r = 0; r < 4; r++) {
      int mrow = wm * 64 + mi * 16 + rq + r;
      if (m0 + mrow < c) {
        float w2 = sW[mrow];
        size_t yrow = (size_t)(offE + m0 + mrow);
#pragma unroll
        for (int ni = 0; ni < 4; ni++) {
          int ncol = n0 + wn * 64 + ni * 16 + ml;
          float v = w2 * acc[mi][ni][r];
          y[yrow * HID + ncol] = (unsigned short)(pack_bf16(v, 0.f) & 0xffffu);
        }
      }
    }
}

// ---------------- OLD PATH (fallback if workspace too small) ----------------

__global__ __launch_bounds__(256, 4) void k_gateup_rs(
    const unsigned short* __restrict__ Ab, const float* __restrict__ w_gate,
    const float* __restrict__ w_up, const int* __restrict__ ws_i,
    __hip_bfloat16* __restrict__ act) {
  __shared__ unsigned short sA[128 * LDA];
  __shared__ unsigned short sBg[64 * LDA];
  __shared__ unsigned short sBu[64 * LDA];

  int bid = blockIdx.x;
  int w = (bid & 7) * (GU_GRID / 8) + (bid >> 3);
  int tileId = w / GU_NB;
  int n0 = (w - tileId * GU_NB) * 64;
  if (tileId >= ws_i[48]) return;
  int e = ws_i[64 + tileId];
  int mt = ws_i[144 + tileId];
  int c = ws_i[e];
  int offE = ws_i[32 + e];
  int m0 = mt * 128;
  int tid = threadIdx.x;
  int lane = tid & 63;
  int wave = tid >> 6;
  int wm = wave & 1, wn = wave >> 1;
  int ar = tid >> 1;
  int ah = (tid & 1) * 16;
  int rA = m0 + ar; int rrA = rA < c ? rA : c - 1;
  const unsigned short* aSrc = Ab + (size_t)(offE + rrA) * HID + ah;
  int bn = tid & 63;
  int bkg = tid >> 6;
  const float* bgSrc = w_gate + (size_t)e * HID * INTER + n0 + bn + (size_t)(bkg * 8) * INTER;
  const float* buSrc = w_up   + (size_t)e * HID * INTER + n0 + bn + (size_t)(bkg * 8) * INTER;

  f32x4 accG[4][2], accU[4][2];
#pragma unroll
  for (int i = 0; i < 4; i++)
#pragma unroll
    for (int j = 0; j < 2; j++) { accG[i][j] = (f32x4)(0.f); accU[i][j] = (f32x4)(0.f); }
  int kq = (lane >> 4) * 8;
  int ml = lane & 15;
  uint4 a0r, a1r; float g[8], u[8];
  {
    const uint4* ap = (const uint4*)aSrc;
    a0r = ap[0]; a1r = ap[1];
#pragma unroll
    for (int j = 0; j < 8; j++) { g[j] = bgSrc[(size_t)j * INTER]; u[j] = buSrc[(size_t)j * INTER]; }
  }
  for (int k0 = 0; k0 < HID; k0 += BK) {
    __syncthreads();
    *(uint4*)&sA[ar * LDA + ah] = a0r;
    *(uint4*)&sA[ar * LDA + ah + 8] = a1r;
    *(uint4*)&sBg[bn * LDA + bkg * 8] = make_uint4(
        pack_bf16(g[0], g[1]), pack_bf16(g[2], g[3]),
        pack_bf16(g[4], g[5]), pack_bf16(g[6], g[7]));
    *(uint4*)&sBu[bn * LDA + bkg * 8] = make_uint4(
        pack_bf16(u[0], u[1]), pack_bf16(u[2], u[3]),
        pack_bf16(u[4], u[5]), pack_bf16(u[6], u[7]));
    __syncthreads();
    if (k0 + BK < HID) {
      const uint4* ap = (const uint4*)(aSrc + k0 + BK);
      a0r = ap[0]; a1r = ap[1];
      const float* bg = bgSrc + (size_t)(k0 + BK) * INTER;
      const float* bu = buSrc + (size_t)(k0 + BK) * INTER;
#pragma unroll
      for (int j = 0; j < 8; j++) { g[j] = bg[(size_t)j * INTER]; u[j] = bu[(size_t)j * INTER]; }
    }
    bf16x8 af[4], bgf[2], buf2[2];
#pragma unroll
    for (int ni = 0; ni < 2; ni++) {
      bgf[ni] = *(const bf16x8*)&sBg[(wn * 32 + ni * 16 + ml) * LDA + kq];
      buf2[ni] = *(const bf16x8*)&sBu[(wn * 32 + ni * 16 + ml) * LDA + kq];
    }
#pragma unroll
    for (int mi = 0; mi < 4; mi++)
      af[mi] = *(const bf16x8*)&sA[(wm * 64 + mi * 16 + ml) * LDA + kq];
#pragma unroll
    for (int mi = 0; mi < 4; mi++)
#pragma unroll
      for (int ni = 0; ni < 2; ni++) {
        accG[mi][ni] = __builtin_amdgcn_mfma_f32_16x16x32_bf16(af[mi], bgf[ni], accG[mi][ni], 0, 0, 0);
        accU[mi][ni] = __builtin_amdgcn_mfma_f32_16x16x32_bf16(af[mi], buf2[ni], accU[mi][ni], 0, 0, 0);
      }
  }
  int rq = (lane >> 4) * 4;
#pragma unroll
  for (int mi = 0; mi < 4; mi++)
#pragma unroll
    for (int r = 0; r < 4; r++) {
      int mrow = wm * 64 + mi * 16 + rq + r;
      int mglob = m0 + mrow;
      if (mglob < c) {
        size_t arow = (size_t)(offE + mglob);
#pragma unroll
        for (int ni = 0; ni < 2; ni++) {
          float gv = accG[mi][ni][r], uv = accU[mi][ni][r];
          float av = gv / (1.f + __expf(-gv)) * uv;
          int ncol = n0 + wn * 32 + ni * 16 + ml;
          act[arow * INTER + ncol] = __float2bfloat16(av);
        }
      }
    }
}

__global__ __launch_bounds__(256, 4) void k_down_rs(
    const __hip_bfloat16* __restrict__ act, const float* __restrict__ w_down,
    const int* __restrict__ ws_i, const float* __restrict__ list_w,
    unsigned short* __restrict__ y) {
  __shared__ unsigned short sA[128 * LDA];
  __shared__ unsigned short sB[64 * LDA];
  __shared__ float sW[128];
  int bid = blockIdx.x;
  int w = (bid & 7) * (DN_GRID / 8) + (bid >> 3);
  int tileId = w >> 5;
  int n0 = (w & 31) * 64;
  if (tileId >= ws_i[48]) return;
  int e = ws_i[64 + tileId];
  int mt = ws_i[144 + tileId];
  int c = ws_i[e];
  int offE = ws_i[32 + e];
  int m0 = mt * 128;
  int tid = threadIdx.x;
  if (tid < 128) {
    int r = m0 + tid;
    int rr = r < c ? r : c - 1;
    sW[tid] = list_w[offE + rr];
  }
  int lane = tid & 63;
  int wave = tid >> 6;
  int wm = wave & 1, wn = wave >> 1;
  f32x4 acc[4][2];
#pragma unroll
  for (int i = 0; i < 4; i++)
#pragma unroll
    for (int j = 0; j < 2; j++) acc[i][j] = (f32x4)(0.f);
  int ar = tid >> 1;
  int ah = (tid & 1) * 16;
  int rA = m0 + ar; int rrA = rA < c ? rA : c - 1;
  const unsigned short* aSrc = (const unsigned short*)act + (size_t)(offE + rrA) * INTER + ah;
  int bn = tid & 63;
  int bkg = tid >> 6;
  const float* bSrc = w_down + (size_t)e * INTER * HID + (size_t)(bkg * 8) * HID + n0 + bn;
  int kq = (lane >> 4) * 8;
  int ml = lane & 15;
  uint4 a0r, a1r; float b[8];
  {
    const uint4* ap = (const uint4*)aSrc;
    a0r = ap[0]; a1r = ap[1];
#pragma unroll
    for (int j = 0; j < 8; j++) b[j] = bSrc[(size_t)j * HID];
  }
  for (int k0 = 0; k0 < INTER; k0 += BK) {
    __syncthreads();
    *(uint4*)&sA[ar * LDA + ah] = a0r;
    *(uint4*)&sA[ar * LDA + ah + 8] = a1r;
    *(uint4*)&sB[bn * LDA + bkg * 8] = make_uint4(
        pack_bf16(b[0], b[1]), pack_bf16(b[2], b[3]),
        pack_bf16(b[4], b[5]), pack_bf16(b[6], b[7]));
    __syncthreads();
    if (k0 + BK < INTER) {
      const uint4* ap = (const uint4*)(aSrc + k0 + BK);
      a0r = ap[0]; a1r = ap[1];
      const float* bp = bSrc + (size_t)(k0 + BK) * HID;
#pragma unroll
      for (int j = 0; j < 8; j++) b[j] = bp[(size_t)j * HID];
    }
    bf16x8 af[4], bf[2];
#pragma unroll
    for (int ni = 0; ni < 2; ni++)
      bf[ni] = *(const bf16x8*)&sB[(wn * 32 + ni * 16 + ml) * LDA + kq];
#pragma unroll
    for (int mi = 0; mi < 4; mi++)
      af[mi] = *(const bf16x8*)&sA[(wm * 64 + mi * 16 + ml) * LDA + kq];
#pragma unroll
    for (int mi = 0; mi < 4; mi++)
#pragma unroll
      for (int ni = 0; ni < 2; ni++)
        acc[mi][ni] = __builtin_amdgcn_mfma_f32_16x16x32_bf16(af[mi], bf[ni], acc[mi][ni], 0, 0, 0);
  }
  int rq = (lane >> 4) * 4;
#pragma unroll
  for (int mi = 0; mi < 4; mi++)
#pragma unroll
    for (int r = 0; r < 4; r++) {
      int mrow = wm * 64 + mi * 16 + rq + r;
      if (m0 + mrow < c) {
        float w2 = sW[mrow];
        size_t yrow = (size_t)(offE + m0 + mrow);
#pragma unroll
        for (int ni = 0; ni < 2; ni++) {
          int ncol = n0 + wn * 32 + ni * 16 + ml;
          float v = w2 * acc[mi][ni][r];
          y[yrow * HID + ncol] = (unsigned short)(pack_bf16(v, 0.f) & 0xffffu);
        }
      }
    }
}

__global__ __launch_bounds__(256) void k_combine(const unsigned short* __restrict__ y,
                                                 const int* __restrict__ slot_of,
                                                 float* __restrict__ out) {
  int t = blockIdx.x, tx = threadIdx.x;
  size_t s0 = (size_t)slot_of[t * 2], s1 = (size_t)slot_of[t * 2 + 1];
  uint4 v0 = ((const uint4*)(y + s0 * HID))[tx];
  uint4 v1 = ((const uint4*)(y + s1 * HID))[tx];
  float r[8];
  unsigned p0[4] = {v0.x, v0.y, v0.z, v0.w};
  unsigned p1[4] = {v1.x, v1.y, v1.z, v1.w};
#pragma unroll
  for (int i = 0; i < 4; i++) {
    float lo0 = __builtin_bit_cast(float, p0[i] << 16);
    float hi0 = __builtin_bit_cast(float, p0[i] & 0xffff0000u);
    float lo1 = __builtin_bit_cast(float, p1[i] << 16);
    float hi1 = __builtin_bit_cast(float, p1[i] & 0xffff0000u);
    r[i * 2] = lo0 + lo1; r[i * 2 + 1] = hi0 + hi1;
  }
  float4* op = (float4*)(out + (size_t)t * HID) + tx * 2;
  op[0] = make_float4(r[0], r[1], r[2], r[3]);
  op[1] = make_float4(r[4], r[5], r[6], r[7]);
}

extern "C" void kernel_launch(void* const* d_in, const int* in_sizes, int n_in,
                              void* d_out, int out_size, void* d_ws, size_t ws_size,
                              hipStream_t stream) {
  const float* hidden = (const float*)d_in[0];
  const float* logits = (const float*)d_in[1];
  const float* w_gate = (const float*)d_in[2];
  const float* w_up = (const float*)d_in[3];
  const float* w_down = (const float*)d_in[4];
  float* out = (float*)d_out;

  int* ws_i = (int*)d_ws;
  int* topk_id = ws_i + 256;
  float* topk_w = (float*)(ws_i + 8448);
  int* list_tok = ws_i + 16640;
  float* list_w = (float*)(ws_i + 24832);
  int* slot_of = ws_i + 33024;
  __hip_bfloat16* act = (__hip_bfloat16*)((char*)d_ws + 262144);
  unsigned short* AbY = (unsigned short*)((char*)d_ws + 23330816);

  hipMemsetAsync(d_ws, 0, 256 * 4, stream);

  k_router<<<NTOK / 256, 256, 0, stream>>>(logits, topk_id, topk_w, ws_i);
  k_build<<<1, 64, 0, stream>>>(ws_i);
  k_scatter<<<NTOK / 256, 256, 0, stream>>>(topk_id, topk_w, ws_i, list_tok, list_w, slot_of);
  k_gather<<<NTOK * 2, 256, 0, stream>>>(hidden, list_tok, AbY);

  if (ws_size >= WS_NEED) {
    unsigned short* wgT = (unsigned short*)((char*)d_ws + WGT_OFF);
    unsigned short* wuT = (unsigned short*)((char*)d_ws + WUT_OFF);
    unsigned short* wdT = (unsigned short*)((char*)d_ws + WDT_OFF);
    k_tconv<<<dim3(INTER / 64, HID / 64, NEXP), 256, 0, stream>>>(w_gate, wgT, HID, INTER);
    k_tconv<<<dim3(INTER / 64, HID / 64, NEXP), 256, 0, stream>>>(w_up, wuT, HID, INTER);
    k_tconv<<<dim3(HID / 64, INTER / 64, NEXP), 256, 0, stream>>>(w_down, wdT, INTER, HID);
    k_gateup_gl<<<GU_GRID, 256, 0, stream>>>(AbY, wgT, wuT, ws_i, act);
    k_down_gl<<<DN_GRID2, 256, 0, stream>>>((const unsigned short*)act, wdT, ws_i, list_w, AbY);
  } else {
    k_gateup_rs<<<GU_GRID, 256, 0, stream>>>(AbY, w_gate, w_up, ws_i, act);
    k_down_rs<<<DN_GRID, 256, 0, stream>>>(act, w_down, ws_i, list_w, AbY);
  }
  k_combine<<<NTOK, 256, 0, stream>>>(AbY, slot_of, out);
}

// Round 3
// 833.645 us; speedup vs baseline: 1.0795x; 1.0246x over previous
//
#include <hip/hip_runtime.h>
#include <hip/hip_bf16.h>
#include <cstdint>

#define NTOK 4096
#define NEXP 16
#define HID 2048
#define INTER 1408
#define BK 32
#define MAXTILES 80
#define GU_NB 22                      // INTER/64 n-blocks
#define DN_NB 16                      // HID/128 n-blocks
#define GU_GRID (GU_NB * MAXTILES)    // 1760, %8==0
#define DN_GRID (DN_NB * MAXTILES)    // 1280, %8==0

typedef __attribute__((ext_vector_type(8))) short bf16x8;
typedef __attribute__((ext_vector_type(4))) float f32x4;

// ws int layout:
//   [0..15]=counts [16..31]=cursors [32..47]=offsets [48]=tile_count
//   [64..143]=tile_e [144..223]=tile_mt
//   [256..]=topk_id(8192) [8448..]=topk_w(8192)
//   [16640..]=list_tok(8192) [24832..]=list_w(8192) [33024..]=slot_of(8192)
// byte 262144: act bf16[8192][1408]
// byte 23330816: AbY bf16[8192][2048] (gathered A, later reused as y)

__device__ inline unsigned pack_bf16(float lo, float hi) {
  unsigned a = __builtin_bit_cast(unsigned, lo) + 0x8000u;
  unsigned b = __builtin_bit_cast(unsigned, hi) + 0x8000u;
  return __builtin_amdgcn_perm(b, a, 0x07060302u); // {b[31:16], a[31:16]}
}

// global -> LDS direct 16B staging (wave-uniform LDS base + lane*16).
typedef __attribute__((address_space(3))) void lds_vt;
typedef __attribute__((address_space(1))) const void glob_vt;
__device__ __forceinline__ void gload16(const void* g, void* l) {
  __builtin_amdgcn_global_load_lds(
      (glob_vt*)(unsigned long long)g,
      (lds_vt*)(unsigned)(unsigned long long)l, 16, 0, 0);
}

__global__ void k_router(const float* __restrict__ logits, int* __restrict__ topk_id,
                         float* __restrict__ topk_w, int* __restrict__ counts) {
  int t = blockIdx.x * blockDim.x + threadIdx.x;
  if (t >= NTOK) return;
  const float* l = logits + (size_t)t * NEXP;
  float b0 = -1e30f, b1 = -1e30f; int i0 = 0, i1 = 0;
#pragma unroll
  for (int i = 0; i < NEXP; i++) {
    float v = l[i];
    if (v > b0) { b1 = b0; i1 = i0; b0 = v; i0 = i; }
    else if (v > b1) { b1 = v; i1 = i; }
  }
  float e = __expf(b1 - b0);
  float inv = 1.f / (1.f + e);
  topk_id[t * 2] = i0; topk_id[t * 2 + 1] = i1;
  topk_w[t * 2] = inv; topk_w[t * 2 + 1] = e * inv;
  atomicAdd(&counts[i0], 1);
  atomicAdd(&counts[i1], 1);
}

__global__ void k_build(int* __restrict__ ws_i) {
  if (threadIdx.x == 0) {
    int off = 0, nt = 0;
    for (int e = 0; e < NEXP; e++) {
      int c = ws_i[e];
      ws_i[32 + e] = off;
      int tiles = (c + 127) >> 7;
      for (int mt = 0; mt < tiles; mt++) { ws_i[64 + nt] = e; ws_i[144 + nt] = mt; nt++; }
      off += c;
    }
    ws_i[48] = nt;
  }
}

__global__ void k_scatter(const int* __restrict__ topk_id, const float* __restrict__ topk_w,
                          int* __restrict__ ws_i, int* __restrict__ list_tok,
                          float* __restrict__ list_w, int* __restrict__ slot_of) {
  int t = blockIdx.x * blockDim.x + threadIdx.x;
  if (t >= NTOK) return;
#pragma unroll
  for (int k = 0; k < 2; k++) {
    int e = topk_id[t * 2 + k];
    int slot = ws_i[32 + e] + atomicAdd(&ws_i[16 + e], 1);
    list_tok[slot] = t;
    list_w[slot] = topk_w[t * 2 + k];
    slot_of[t * 2 + k] = slot;
  }
}

__global__ __launch_bounds__(256) void k_gather(const float* __restrict__ hidden,
                                                const int* __restrict__ list_tok,
                                                unsigned short* __restrict__ Ab) {
  int s = blockIdx.x, tx = threadIdx.x;
  int t = list_tok[s];
  const float4* src = (const float4*)(hidden + (size_t)t * HID) + tx * 2;
  float4 a = src[0], b = src[1];
  uint4 w = make_uint4(pack_bf16(a.x, a.y), pack_bf16(a.z, a.w),
                       pack_bf16(b.x, b.y), pack_bf16(b.z, b.w));
  ((uint4*)(Ab + (size_t)s * HID))[tx] = w;
}

// gate+up GEMM + SwiGLU, fused fp32->bf16 weight conversion.
// Tile 128m x 64n (g,u), BK=32, 4 waves 2m x 2n.
// A: bf16, global_load_lds into linear [128][32].
// B: fp32 rows staged via global_load_lds into linear [32][64]; fragments
//    built per-thread with 8 strided ds_read_b32 + pack (k-contiguous bf16x8).
__global__ __launch_bounds__(256, 3) void k_gateup_f(
    const unsigned short* __restrict__ Ab, const float* __restrict__ w_gate,
    const float* __restrict__ w_up, const int* __restrict__ ws_i,
    __hip_bfloat16* __restrict__ act) {
  __shared__ unsigned short sA[128 * BK];   // 8 KB bf16 [128][32]
  __shared__ float sG[BK * 64];             // 8 KB fp32 [32][64], 256 B rows
  __shared__ float sU[BK * 64];             // 8 KB

  int bid = blockIdx.x;
  int w = (bid & 7) * (GU_GRID / 8) + (bid >> 3);  // XCD-chunked bijection
  int tileId = w / GU_NB;
  int n0 = (w - tileId * GU_NB) * 64;
  if (tileId >= ws_i[48]) return;
  int e = ws_i[64 + tileId];
  int mt = ws_i[144 + tileId];
  int c = ws_i[e];
  int offE = ws_i[32 + e];
  int m0 = mt * 128;
  int tid = threadIdx.x;
  int lane = tid & 63;
  int wave = tid >> 6;
  int wm = wave & 1, wn = wave >> 1;

  // A staging: wave covers rows wave*32..+31 (64 B rows), two 1024 B chunks
  int la = lane >> 2;
  int h = (lane & 3) * 16;
  int gr0 = m0 + wave * 32 + la;      gr0 = gr0 < c ? gr0 : c - 1;
  int gr1 = m0 + wave * 32 + 16 + la; gr1 = gr1 < c ? gr1 : c - 1;
  const char* aBase0 = (const char*)(Ab + (size_t)(offE + gr0) * HID) + h;
  const char* aBase1 = (const char*)(Ab + (size_t)(offE + gr1) * HID) + h;
  char* ldsA0 = (char*)sA + (wave * 2 + 0) * 1024;
  char* ldsA1 = (char*)sA + (wave * 2 + 1) * 1024;

  // B fp32 staging: wave covers k-rows wave*8..+7 (256 B rows), two chunks of 4 rows
  int kr = lane >> 4;            // row within 4-row chunk
  int hb = (lane & 15) * 16;     // byte within 256 B row
  int kB0 = wave * 8 + kr;
  int kB1 = wave * 8 + 4 + kr;
  const char* gBase0 = (const char*)(w_gate + (size_t)e * HID * INTER + (size_t)kB0 * INTER + n0) + hb;
  const char* gBase1 = (const char*)(w_gate + (size_t)e * HID * INTER + (size_t)kB1 * INTER + n0) + hb;
  const char* uBase0 = (const char*)(w_up   + (size_t)e * HID * INTER + (size_t)kB0 * INTER + n0) + hb;
  const char* uBase1 = (const char*)(w_up   + (size_t)e * HID * INTER + (size_t)kB1 * INTER + n0) + hb;
  char* ldsG0 = (char*)sG + (wave * 2 + 0) * 1024;
  char* ldsG1 = (char*)sG + (wave * 2 + 1) * 1024;
  char* ldsU0 = (char*)sU + (wave * 2 + 0) * 1024;
  char* ldsU1 = (char*)sU + (wave * 2 + 1) * 1024;

  f32x4 accG[4][2], accU[4][2];
#pragma unroll
  for (int i = 0; i < 4; i++)
#pragma unroll
    for (int j = 0; j < 2; j++) { accG[i][j] = (f32x4)(0.f); accU[i][j] = (f32x4)(0.f); }

  int kq = (lane >> 4) * 8;
  int ml = lane & 15;
  int nB0 = wn * 32 + ml;

  for (int k0 = 0; k0 < HID; k0 += BK) {
    __syncthreads();                       // prev-iter LDS reads done
    size_t ab = (size_t)k0 * 2;            // A byte advance (bf16)
    size_t bb = (size_t)k0 * INTER * 4;    // B byte advance (fp32 rows)
    gload16(aBase0 + ab, ldsA0);
    gload16(aBase1 + ab, ldsA1);
    gload16(gBase0 + bb, ldsG0);
    gload16(gBase1 + bb, ldsG1);
    gload16(uBase0 + bb, ldsU0);
    gload16(uBase1 + bb, ldsU1);
    __syncthreads();                       // vmcnt drain -> LDS ready

    bf16x8 af[4], bgf[2], buf2[2];
#pragma unroll
    for (int mi = 0; mi < 4; mi++)
      af[mi] = *(const bf16x8*)&sA[(wm * 64 + mi * 16 + ml) * BK + kq];
#pragma unroll
    for (int ni = 0; ni < 2; ni++) {
      int nb = nB0 + ni * 16;
      float tg[8], tu[8];
#pragma unroll
      for (int i = 0; i < 8; i++) {
        tg[i] = sG[(kq + i) * 64 + nb];
        tu[i] = sU[(kq + i) * 64 + nb];
      }
      union { uint4 q; bf16x8 v; } cg, cu;
      cg.q = make_uint4(pack_bf16(tg[0], tg[1]), pack_bf16(tg[2], tg[3]),
                        pack_bf16(tg[4], tg[5]), pack_bf16(tg[6], tg[7]));
      cu.q = make_uint4(pack_bf16(tu[0], tu[1]), pack_bf16(tu[2], tu[3]),
                        pack_bf16(tu[4], tu[5]), pack_bf16(tu[6], tu[7]));
      bgf[ni] = cg.v; buf2[ni] = cu.v;
    }
#pragma unroll
    for (int mi = 0; mi < 4; mi++)
#pragma unroll
      for (int ni = 0; ni < 2; ni++) {
        accG[mi][ni] = __builtin_amdgcn_mfma_f32_16x16x32_bf16(af[mi], bgf[ni], accG[mi][ni], 0, 0, 0);
        accU[mi][ni] = __builtin_amdgcn_mfma_f32_16x16x32_bf16(af[mi], buf2[ni], accU[mi][ni], 0, 0, 0);
      }
  }

  // epilogue: act = silu(g)*u. C/D: col=lane&15, row=(lane>>4)*4+reg
  int rq = (lane >> 4) * 4;
#pragma unroll
  for (int mi = 0; mi < 4; mi++)
#pragma unroll
    for (int r = 0; r < 4; r++) {
      int mrow = wm * 64 + mi * 16 + rq + r;
      int mglob = m0 + mrow;
      if (mglob < c) {
        size_t arow = (size_t)(offE + mglob);
#pragma unroll
        for (int ni = 0; ni < 2; ni++) {
          float gv = accG[mi][ni][r], uv = accU[mi][ni][r];
          float av = gv / (1.f + __expf(-gv)) * uv;
          int ncol = n0 + wn * 32 + ni * 16 + ml;
          act[arow * INTER + ncol] = __float2bfloat16(av);
        }
      }
    }
}

// down GEMM, weighted, fused fp32->bf16 weight conversion.
// Tile 128m x 128n, BK=32, 4 waves 2m x 2n. B fp32 [32][128] staged via gload16.
__global__ __launch_bounds__(256, 3) void k_down_f(
    const unsigned short* __restrict__ act, const float* __restrict__ w_down,
    const int* __restrict__ ws_i, const float* __restrict__ list_w,
    unsigned short* __restrict__ y) {
  __shared__ unsigned short sA[128 * BK];   // 8 KB
  __shared__ float sB[BK * 128];            // 16 KB fp32 [32][128], 512 B rows
  __shared__ float sW[128];

  int bid = blockIdx.x;
  int w = (bid & 7) * (DN_GRID / 8) + (bid >> 3);
  int tileId = w >> 4;
  int n0 = (w & 15) * 128;
  if (tileId >= ws_i[48]) return;
  int e = ws_i[64 + tileId];
  int mt = ws_i[144 + tileId];
  int c = ws_i[e];
  int offE = ws_i[32 + e];
  int m0 = mt * 128;
  int tid = threadIdx.x;

  if (tid < 128) {
    int r = m0 + tid;
    int rr = r < c ? r : c - 1;
    sW[tid] = list_w[offE + rr];
  }

  int lane = tid & 63;
  int wave = tid >> 6;
  int wm = wave & 1, wn = wave >> 1;

  // A staging
  int la = lane >> 2;
  int h = (lane & 3) * 16;
  int gr0 = m0 + wave * 32 + la;      gr0 = gr0 < c ? gr0 : c - 1;
  int gr1 = m0 + wave * 32 + 16 + la; gr1 = gr1 < c ? gr1 : c - 1;
  const char* aBase0 = (const char*)(act + (size_t)(offE + gr0) * INTER) + h;
  const char* aBase1 = (const char*)(act + (size_t)(offE + gr1) * INTER) + h;
  char* ldsA0 = (char*)sA + (wave * 2 + 0) * 1024;
  char* ldsA1 = (char*)sA + (wave * 2 + 1) * 1024;

  // B fp32 staging: wave covers k-rows wave*8..+7 (512 B rows), 4 chunks of 2 rows
  int krd = lane >> 5;           // row within 2-row chunk
  int hd = (lane & 31) * 16;     // byte within 512 B row
  const char* bRoot = (const char*)(w_down + (size_t)e * INTER * HID + n0);
  char* ldsBw = (char*)sB + wave * 4096;

  f32x4 acc[4][4];
#pragma unroll
  for (int i = 0; i < 4; i++)
#pragma unroll
    for (int j = 0; j < 4; j++) acc[i][j] = (f32x4)(0.f);

  int kq = (lane >> 4) * 8;
  int ml = lane & 15;
  int nB0 = wn * 64 + ml;

  for (int k0 = 0; k0 < INTER; k0 += BK) {
    __syncthreads();
    size_t ab = (size_t)k0 * 2;
    gload16(aBase0 + ab, ldsA0);
    gload16(aBase1 + ab, ldsA1);
#pragma unroll
    for (int cch = 0; cch < 4; cch++) {
      size_t kk = (size_t)(k0 + wave * 8 + cch * 2 + krd);
      gload16(bRoot + kk * HID * 4 + hd, ldsBw + cch * 1024);
    }
    __syncthreads();

    bf16x8 af[4], bf[4];
#pragma unroll
    for (int mi = 0; mi < 4; mi++)
      af[mi] = *(const bf16x8*)&sA[(wm * 64 + mi * 16 + ml) * BK + kq];
#pragma unroll
    for (int ni = 0; ni < 4; ni++) {
      int nb = nB0 + ni * 16;
      float t[8];
#pragma unroll
      for (int i = 0; i < 8; i++) t[i] = sB[(kq + i) * 128 + nb];
      union { uint4 q; bf16x8 v; } cb;
      cb.q = make_uint4(pack_bf16(t[0], t[1]), pack_bf16(t[2], t[3]),
                        pack_bf16(t[4], t[5]), pack_bf16(t[6], t[7]));
      bf[ni] = cb.v;
    }
#pragma unroll
    for (int mi = 0; mi < 4; mi++)
#pragma unroll
      for (int ni = 0; ni < 4; ni++)
        acc[mi][ni] = __builtin_amdgcn_mfma_f32_16x16x32_bf16(af[mi], bf[ni], acc[mi][ni], 0, 0, 0);
  }

  int rq = (lane >> 4) * 4;
#pragma unroll
  for (int mi = 0; mi < 4; mi++)
#pragma unroll
    for (int r = 0; r < 4; r++) {
      int mrow = wm * 64 + mi * 16 + rq + r;
      if (m0 + mrow < c) {
        float w2 = sW[mrow];
        size_t yrow = (size_t)(offE + m0 + mrow);
#pragma unroll
        for (int ni = 0; ni < 4; ni++) {
          int ncol = n0 + wn * 64 + ni * 16 + ml;
          float v = w2 * acc[mi][ni][r];
          y[yrow * HID + ncol] = (unsigned short)(pack_bf16(v, 0.f) & 0xffffu);
        }
      }
    }
}

// out[t] = y[slot0] + y[slot1], full coalesced row writes.
__global__ __launch_bounds__(256) void k_combine(const unsigned short* __restrict__ y,
                                                 const int* __restrict__ slot_of,
                                                 float* __restrict__ out) {
  int t = blockIdx.x, tx = threadIdx.x;
  size_t s0 = (size_t)slot_of[t * 2], s1 = (size_t)slot_of[t * 2 + 1];
  uint4 v0 = ((const uint4*)(y + s0 * HID))[tx];
  uint4 v1 = ((const uint4*)(y + s1 * HID))[tx];
  float r[8];
  unsigned p0[4] = {v0.x, v0.y, v0.z, v0.w};
  unsigned p1[4] = {v1.x, v1.y, v1.z, v1.w};
#pragma unroll
  for (int i = 0; i < 4; i++) {
    float lo0 = __builtin_bit_cast(float, p0[i] << 16);
    float hi0 = __builtin_bit_cast(float, p0[i] & 0xffff0000u);
    float lo1 = __builtin_bit_cast(float, p1[i] << 16);
    float hi1 = __builtin_bit_cast(float, p1[i] & 0xffff0000u);
    r[i * 2] = lo0 + lo1; r[i * 2 + 1] = hi0 + hi1;
  }
  float4* op = (float4*)(out + (size_t)t * HID) + tx * 2;
  op[0] = make_float4(r[0], r[1], r[2], r[3]);
  op[1] = make_float4(r[4], r[5], r[6], r[7]);
}

extern "C" void kernel_launch(void* const* d_in, const int* in_sizes, int n_in,
                              void* d_out, int out_size, void* d_ws, size_t ws_size,
                              hipStream_t stream) {
  const float* hidden = (const float*)d_in[0];
  const float* logits = (const float*)d_in[1];
  const float* w_gate = (const float*)d_in[2];
  const float* w_up = (const float*)d_in[3];
  const float* w_down = (const float*)d_in[4];
  float* out = (float*)d_out;

  int* ws_i = (int*)d_ws;
  int* topk_id = ws_i + 256;
  float* topk_w = (float*)(ws_i + 8448);
  int* list_tok = ws_i + 16640;
  float* list_w = (float*)(ws_i + 24832);
  int* slot_of = ws_i + 33024;
  __hip_bfloat16* act = (__hip_bfloat16*)((char*)d_ws + 262144);
  unsigned short* AbY = (unsigned short*)((char*)d_ws + 23330816);

  hipMemsetAsync(d_ws, 0, 256 * 4, stream);

  k_router<<<NTOK / 256, 256, 0, stream>>>(logits, topk_id, topk_w, ws_i);
  k_build<<<1, 64, 0, stream>>>(ws_i);
  k_scatter<<<NTOK / 256, 256, 0, stream>>>(topk_id, topk_w, ws_i, list_tok, list_w, slot_of);
  k_gather<<<NTOK * 2, 256, 0, stream>>>(hidden, list_tok, AbY);
  k_gateup_f<<<GU_GRID, 256, 0, stream>>>(AbY, w_gate, w_up, ws_i, act);
  k_down_f<<<DN_GRID, 256, 0, stream>>>((const unsigned short*)act, w_down, ws_i, list_w, AbY);
  k_combine<<<NTOK, 256, 0, stream>>>(AbY, slot_of, out);
}